// Round 3
// baseline (301.795 us; speedup 1.0000x reference)
//
#include <hip/hip_runtime.h>

#define NEG_SLOPE 0.2f
#define EPSV 1e-16f
#define NHEADS 8
#define NCH 16
#define BKT_SHIFT 8        // 256 nodes per bucket
#define BKT_NODES 256
#define CAP 8192           // per-bucket edge capacity (mean 4096, ~64 sigma slack)
#define BIN_EPB 4096       // edges per block in bin pass (16/thread)
#define MAX_BKT 512

// Setup: zero the bucket cursors (S1/D1 now computed per-block in gather1).
__global__ __launch_bounds__(512) void gat_setup_kernel(
        int* __restrict__ bkt_cnt, int nbuckets) {
    int t = threadIdx.x;
    for (int i = t; i < nbuckets; i += 512) bkt_cnt[i] = 0;
}

// Bin pass (round-0 proven): LDS histogram -> local ranks; one global atomic
// per (block, nonempty bucket); packed (src<<8 | dst&255) writes.
__global__ __launch_bounds__(256) void gat_bin_kernel(
        const int* __restrict__ ei, int E, int nbuckets,
        int* __restrict__ bkt_cnt, unsigned int* __restrict__ binned) {
    __shared__ int hist[MAX_BKT];
    __shared__ int gbase[MAX_BKT];
    int t = threadIdx.x;
    for (int i = t; i < nbuckets; i += 256) hist[i] = 0;
    __syncthreads();
    int base = blockIdx.x * BIN_EPB;
    int lr[16];
#pragma unroll
    for (int k = 0; k < 4; ++k) {
        int idx = base + k * 1024 + t * 4;
        if (idx + 3 < E) {
            int4 d4 = *(const int4*)(ei + E + idx);
            lr[4*k+0] = atomicAdd(&hist[d4.x >> BKT_SHIFT], 1);
            lr[4*k+1] = atomicAdd(&hist[d4.y >> BKT_SHIFT], 1);
            lr[4*k+2] = atomicAdd(&hist[d4.z >> BKT_SHIFT], 1);
            lr[4*k+3] = atomicAdd(&hist[d4.w >> BKT_SHIFT], 1);
        } else {
            for (int u = 0; u < 4; ++u)
                if (idx + u < E)
                    lr[4*k+u] = atomicAdd(&hist[ei[E + idx + u] >> BKT_SHIFT], 1);
        }
    }
    __syncthreads();
    for (int i = t; i < nbuckets; i += 256) {
        int c = hist[i];
        gbase[i] = c ? (i * CAP + atomicAdd(&bkt_cnt[i], c)) : 0;
    }
    __syncthreads();
#pragma unroll
    for (int k = 0; k < 4; ++k) {
        int idx = base + k * 1024 + t * 4;
        if (idx + 3 < E) {
            int4 s4 = *(const int4*)(ei + idx);
            int4 d4 = *(const int4*)(ei + E + idx);
            binned[gbase[d4.x >> BKT_SHIFT] + lr[4*k+0]] =
                ((unsigned)s4.x << BKT_SHIFT) | (unsigned)(d4.x & (BKT_NODES-1));
            binned[gbase[d4.y >> BKT_SHIFT] + lr[4*k+1]] =
                ((unsigned)s4.y << BKT_SHIFT) | (unsigned)(d4.y & (BKT_NODES-1));
            binned[gbase[d4.z >> BKT_SHIFT] + lr[4*k+2]] =
                ((unsigned)s4.z << BKT_SHIFT) | (unsigned)(d4.z & (BKT_NODES-1));
            binned[gbase[d4.w >> BKT_SHIFT] + lr[4*k+3]] =
                ((unsigned)s4.w << BKT_SHIFT) | (unsigned)(d4.w & (BKT_NODES-1));
        } else {
            for (int u = 0; u < 4; ++u)
                if (idx + u < E) {
                    unsigned s = (unsigned)ei[idx + u];
                    int d = ei[E + idx + u];
                    binned[gbase[d >> BKT_SHIFT] + lr[4*k+u]] =
                        (s << BKT_SHIFT) | (unsigned)(d & (BKT_NODES-1));
                }
        }
    }
}

// Layer 1, edge-parallel: no sort, no degree straggler. Per-bucket LDS
// accumulators den/num[256][8]; 512 threads (8 waves) for latency hiding.
// Fused MLP epilogue writes h2.
__global__ __launch_bounds__(512) void gat_gather1_kernel(
        int N, const float* __restrict__ x,
        const unsigned int* __restrict__ binned, const int* __restrict__ bkt_cnt,
        const float* __restrict__ W1, const float* __restrict__ as1,
        const float* __restrict__ ad1, const float* __restrict__ b1,
        const float* __restrict__ W2, float* __restrict__ h2out) {
    __shared__ float den[BKT_NODES][NHEADS];   // 8 KB
    __shared__ float num[BKT_NODES][NHEADS];   // 8 KB
    __shared__ float xloc[BKT_NODES];
    __shared__ float S1s[NHEADS], D1s[NHEADS];
    int b = blockIdx.x, t = threadIdx.x;
    if (t < NHEADS) {
        float s = 0.f, d = 0.f;
        for (int c = 0; c < NCH; ++c) {
            float w = W1[t * NCH + c];
            s += w * as1[t * NCH + c];
            d += w * ad1[t * NCH + c];
        }
        S1s[t] = s; D1s[t] = d;
    }
    __syncthreads();
    int node = (b << BKT_SHIFT) + (t & (BKT_NODES - 1));
    if (t < BKT_NODES) {
        float xn = (node < N) ? x[node] : 0.f;
        xloc[t] = xn;
#pragma unroll
        for (int h = 0; h < NHEADS; ++h) {
            float e = xn * S1s[h] + xn * D1s[h];    // self-loop
            e = e > 0.f ? e : NEG_SLOPE * e;
            float ex = __expf(e);
            den[t][h] = ex + EPSV;
            num[t][h] = ex * xn;
        }
    }
    __syncthreads();
    // hoist attention scalars to registers
    float S1[NHEADS], D1[NHEADS];
#pragma unroll
    for (int h = 0; h < NHEADS; ++h) { S1[h] = S1s[h]; D1[h] = D1s[h]; }
    int nE = bkt_cnt[b]; if (nE > CAP) nE = CAP;
    const unsigned int* bb = binned + (size_t)b * CAP;
    for (int j0 = 0; j0 < nE; j0 += 2048) {
        int idx = j0 + t * 4;
        unsigned v[4];
        int nv;
        if (idx + 3 < nE) {
            uint4 q = *(const uint4*)(bb + idx);
            v[0] = q.x; v[1] = q.y; v[2] = q.z; v[3] = q.w; nv = 4;
        } else {
            nv = nE - idx; if (nv < 0) nv = 0; if (nv > 4) nv = 4;
            for (int u = 0; u < nv; ++u) v[u] = bb[idx + u];
        }
        for (int u = 0; u < nv; ++u) {
            unsigned s = v[u] >> BKT_SHIFT;
            int dl = v[u] & (BKT_NODES - 1);
            float xs = x[s];
            float xd = xloc[dl];
#pragma unroll
            for (int h = 0; h < NHEADS; ++h) {
                float e = xs * S1[h] + xd * D1[h];
                e = e > 0.f ? e : NEG_SLOPE * e;
                float f = __expf(e);
                atomicAdd(&den[dl][h], f);
                atomicAdd(&num[dl][h], f * xs);
            }
        }
    }
    __syncthreads();
    if (t < BKT_NODES && node < N) {
        float acc = 0.f;
#pragma unroll
        for (int h = 0; h < NHEADS; ++h) {
            float z = num[t][h] / den[t][h];
#pragma unroll
            for (int cc = 0; cc < NCH; ++cc) {
                int k = h * NCH + cc;
                float vv = W1[k] * z + b1[k];
                vv = vv > 0.f ? vv : (__expf(vv) - 1.f);   // elu
                acc += vv * W2[k];
            }
        }
        h2out[node] = acc;
    }
}

// Layer 2, edge-parallel straight from binned (no sorted write-back needed).
__global__ __launch_bounds__(512) void gat_gather2_kernel(
        int N, const float* __restrict__ h2,
        const unsigned int* __restrict__ binned, const int* __restrict__ bkt_cnt,
        const float* __restrict__ as2p, const float* __restrict__ ad2p,
        const float* __restrict__ b2, float* __restrict__ out) {
    __shared__ float den2[BKT_NODES];
    __shared__ float num2[BKT_NODES];
    __shared__ float hloc[BKT_NODES];
    int b = blockIdx.x, t = threadIdx.x;
    float a_s = as2p[0], a_d = ad2p[0];
    int node = (b << BKT_SHIFT) + (t & (BKT_NODES - 1));
    if (t < BKT_NODES) {
        float hn = (node < N) ? h2[node] : 0.f;
        hloc[t] = hn;
        float e = hn * a_s + hn * a_d;              // self-loop
        e = e > 0.f ? e : NEG_SLOPE * e;
        float ex = __expf(e);
        den2[t] = ex + EPSV;
        num2[t] = ex * hn;
    }
    __syncthreads();
    int nE = bkt_cnt[b]; if (nE > CAP) nE = CAP;
    const unsigned int* bb = binned + (size_t)b * CAP;
    for (int j0 = 0; j0 < nE; j0 += 2048) {
        int idx = j0 + t * 4;
        unsigned v[4];
        int nv;
        if (idx + 3 < nE) {
            uint4 q = *(const uint4*)(bb + idx);
            v[0] = q.x; v[1] = q.y; v[2] = q.z; v[3] = q.w; nv = 4;
        } else {
            nv = nE - idx; if (nv < 0) nv = 0; if (nv > 4) nv = 4;
            for (int u = 0; u < nv; ++u) v[u] = bb[idx + u];
        }
        for (int u = 0; u < nv; ++u) {
            unsigned s = v[u] >> BKT_SHIFT;
            int dl = v[u] & (BKT_NODES - 1);
            float hs = h2[s];
            float e = hs * a_s + hloc[dl] * a_d;
            e = e > 0.f ? e : NEG_SLOPE * e;
            float f = __expf(e);
            atomicAdd(&den2[dl], f);
            atomicAdd(&num2[dl], f * hs);
        }
    }
    __syncthreads();
    if (t < BKT_NODES && node < N)
        out[node] = num2[t] / den2[t] + b2[0];
}

extern "C" void kernel_launch(void* const* d_in, const int* in_sizes, int n_in,
                              void* d_out, int out_size, void* d_ws, size_t ws_size,
                              hipStream_t stream) {
    const float* x   = (const float*)d_in[0];
    const int*   ei  = (const int*)d_in[1];
    const float* W1  = (const float*)d_in[2];
    const float* as1 = (const float*)d_in[3];
    const float* ad1 = (const float*)d_in[4];
    const float* b1  = (const float*)d_in[5];
    const float* W2  = (const float*)d_in[6];
    const float* as2 = (const float*)d_in[7];
    const float* ad2 = (const float*)d_in[8];
    const float* b2  = (const float*)d_in[9];
    float* out = (float*)d_out;

    int N = in_sizes[0];       // 100000
    int E = in_sizes[1] / 2;   // 1600000

    int nbuckets = (N + BKT_NODES - 1) >> BKT_SHIFT;   // 391
    int nbin     = (E + BIN_EPB - 1) / BIN_EPB;        // 391

    // Workspace: h2[N]f | bkt_cnt[nbuckets]i | binned[nbuckets*CAP]u (~13 MB)
    float* h2      = (float*)d_ws;
    int*   bkt_cnt = (int*)(h2 + N);
    unsigned int* binned = (unsigned int*)(bkt_cnt + nbuckets);

    gat_setup_kernel<<<1, 512, 0, stream>>>(bkt_cnt, nbuckets);
    gat_bin_kernel<<<nbin, 256, 0, stream>>>(ei, E, nbuckets, bkt_cnt, binned);
    gat_gather1_kernel<<<nbuckets, 512, 0, stream>>>(N, x, binned, bkt_cnt,
                                                     W1, as1, ad1, b1, W2, h2);
    gat_gather2_kernel<<<nbuckets, 512, 0, stream>>>(N, h2, binned, bkt_cnt,
                                                     as2, ad2, b2, out);
}

// Round 4
// 209.903 us; speedup vs baseline: 1.4378x; 1.4378x over previous
//
#include <hip/hip_runtime.h>

#define NEG_SLOPE 0.2f
#define EPSV 1e-16f
#define NHEADS 8
#define NCH 16
#define SLOT 48            // per-node adjacency capacity; Poisson(16) max over 1e5 ~ 40
#define OVF_CAP 8192
#define SCAT_EPB 4096      // edges per scatter block (16/thread)

// Scatter: one global atomicAdd per edge gives the per-node rank; write src
// directly into the node's fixed-stride slot. No LDS atomics, no sort, no
// write-back. Overflow (deg > SLOT, ~impossible for this input) goes to a
// guarded side list.
__global__ __launch_bounds__(256) void gat_scatter_kernel(
        const int* __restrict__ ei, int E,
        int* __restrict__ deg, int* __restrict__ ovf_cnt,
        unsigned long long* __restrict__ ovf,
        unsigned int* __restrict__ binned) {
    int t = threadIdx.x;
    int base = blockIdx.x * SCAT_EPB;
#pragma unroll
    for (int k = 0; k < 4; ++k) {
        int idx = base + k * 1024 + t * 4;
        int sv[4], dv[4], ne;
        if (idx + 3 < E) {
            int4 s4 = *(const int4*)(ei + idx);
            int4 d4 = *(const int4*)(ei + E + idx);
            sv[0] = s4.x; sv[1] = s4.y; sv[2] = s4.z; sv[3] = s4.w;
            dv[0] = d4.x; dv[1] = d4.y; dv[2] = d4.z; dv[3] = d4.w;
            ne = 4;
        } else {
            ne = E - idx; if (ne < 0) ne = 0; if (ne > 4) ne = 4;
            for (int u = 0; u < ne; ++u) { sv[u] = ei[idx + u]; dv[u] = ei[E + idx + u]; }
        }
#pragma unroll
        for (int u = 0; u < 4; ++u) {
            if (u >= ne) break;
            int d = dv[u];
            int r = atomicAdd(&deg[d], 1);
            if (r < SLOT) {
                binned[(size_t)d * SLOT + r] = (unsigned)sv[u];
            } else {
                int o = atomicAdd(ovf_cnt, 1);
                if (o < OVF_CAP)
                    ovf[o] = ((unsigned long long)(unsigned)sv[u] << 32) | (unsigned)d;
            }
        }
    }
}

// Layer 1: node-parallel gather over the fixed-stride adjacency + fused
// per-node MLP (128-dim elu + W2 projection) -> h2.
__global__ __launch_bounds__(256) void gat_gather1_kernel(
        int N, const float* __restrict__ x,
        const unsigned int* __restrict__ binned, const int* __restrict__ deg,
        const int* __restrict__ ovf_cnt, const unsigned long long* __restrict__ ovf,
        const float* __restrict__ W1, const float* __restrict__ as1,
        const float* __restrict__ ad1, const float* __restrict__ b1,
        const float* __restrict__ W2, float* __restrict__ h2out) {
    __shared__ float S1s[NHEADS], D1s[NHEADS];
    int t = threadIdx.x;
    if (t < NHEADS) {
        float s = 0.f, d = 0.f;
        for (int c = 0; c < NCH; ++c) {
            float w = W1[t * NCH + c];
            s += w * as1[t * NCH + c];
            d += w * ad1[t * NCH + c];
        }
        S1s[t] = s; D1s[t] = d;
    }
    __syncthreads();
    int n = blockIdx.x * 256 + t;
    if (n >= N) return;
    float S1[NHEADS], D1[NHEADS], den[NHEADS], num[NHEADS];
    float xn = x[n];
#pragma unroll
    for (int h = 0; h < NHEADS; ++h) {
        S1[h] = S1s[h]; D1[h] = D1s[h];
        float e = xn * S1[h] + xn * D1[h];          // self-loop
        e = e > 0.f ? e : NEG_SLOPE * e;
        float ex = __expf(e);
        den[h] = ex + EPSV;
        num[h] = ex * xn;
    }
    int dg = deg[n];
    int c = dg < SLOT ? dg : SLOT;
    const unsigned int* bb = binned + (size_t)n * SLOT;
    float A[NHEADS];
#pragma unroll
    for (int h = 0; h < NHEADS; ++h) A[h] = xn * D1[h];
    int j = 0;
    for (; j + 4 <= c; j += 4) {
        uint4 q = *(const uint4*)(bb + j);           // 16B-aligned (SLOT*4=192)
        float x0 = x[q.x], x1 = x[q.y], x2 = x[q.z], x3 = x[q.w];
#pragma unroll
        for (int h = 0; h < NHEADS; ++h) {
            float ea = x0 * S1[h] + A[h]; ea = ea > 0.f ? ea : NEG_SLOPE * ea;
            float eb = x1 * S1[h] + A[h]; eb = eb > 0.f ? eb : NEG_SLOPE * eb;
            float ec = x2 * S1[h] + A[h]; ec = ec > 0.f ? ec : NEG_SLOPE * ec;
            float ee = x3 * S1[h] + A[h]; ee = ee > 0.f ? ee : NEG_SLOPE * ee;
            float fa = __expf(ea), fb = __expf(eb), fc = __expf(ec), fd = __expf(ee);
            den[h] += (fa + fb) + (fc + fd);
            num[h] += (fa * x0 + fb * x1) + (fc * x2 + fd * x3);
        }
    }
    for (; j < c; ++j) {
        unsigned s = bb[j];
        float x0 = x[s];
#pragma unroll
        for (int h = 0; h < NHEADS; ++h) {
            float ea = x0 * S1[h] + A[h];
            ea = ea > 0.f ? ea : NEG_SLOPE * ea;
            float fa = __expf(ea);
            den[h] += fa;
            num[h] += fa * x0;
        }
    }
    if (dg > SLOT) {                                 // overflow scan (normally 0)
        int on = *ovf_cnt; if (on > OVF_CAP) on = OVF_CAP;
        for (int i = 0; i < on; ++i) {
            unsigned long long e64 = ovf[i];
            if ((int)(e64 & 0xFFFFFFFFu) == n) {
                float x0 = x[(unsigned)(e64 >> 32)];
#pragma unroll
                for (int h = 0; h < NHEADS; ++h) {
                    float ea = x0 * S1[h] + A[h];
                    ea = ea > 0.f ? ea : NEG_SLOPE * ea;
                    float fa = __expf(ea);
                    den[h] += fa;
                    num[h] += fa * x0;
                }
            }
        }
    }
    float acc = 0.f;
#pragma unroll
    for (int h = 0; h < NHEADS; ++h) {
        float z = num[h] / den[h];
#pragma unroll
        for (int cc = 0; cc < NCH; ++cc) {
            int k = h * NCH + cc;
            float vv = W1[k] * z + b1[k];
            vv = vv > 0.f ? vv : (__expf(vv) - 1.f);   // elu
            acc += vv * W2[k];
        }
    }
    h2out[n] = acc;
}

// Layer 2: node-parallel gather over the SAME adjacency (no rebuild).
__global__ __launch_bounds__(256) void gat_gather2_kernel(
        int N, const float* __restrict__ h2,
        const unsigned int* __restrict__ binned, const int* __restrict__ deg,
        const int* __restrict__ ovf_cnt, const unsigned long long* __restrict__ ovf,
        const float* __restrict__ as2p, const float* __restrict__ ad2p,
        const float* __restrict__ b2, float* __restrict__ out) {
    int n = blockIdx.x * 256 + threadIdx.x;
    if (n >= N) return;
    float a_s = as2p[0], a_d = ad2p[0];
    float hn = h2[n];
    float ad = hn * a_d;
    float e = hn * a_s + ad;                         // self-loop
    e = e > 0.f ? e : NEG_SLOPE * e;
    float ex = __expf(e);
    float den = ex + EPSV;
    float num = ex * hn;
    int dg = deg[n];
    int c = dg < SLOT ? dg : SLOT;
    const unsigned int* bb = binned + (size_t)n * SLOT;
    int j = 0;
    for (; j + 4 <= c; j += 4) {
        uint4 q = *(const uint4*)(bb + j);
        float h0 = h2[q.x], h1 = h2[q.y], h3 = h2[q.z], h4 = h2[q.w];
        float ea = h0 * a_s + ad; ea = ea > 0.f ? ea : NEG_SLOPE * ea;
        float eb = h1 * a_s + ad; eb = eb > 0.f ? eb : NEG_SLOPE * eb;
        float ec = h3 * a_s + ad; ec = ec > 0.f ? ec : NEG_SLOPE * ec;
        float ee = h4 * a_s + ad; ee = ee > 0.f ? ee : NEG_SLOPE * ee;
        float fa = __expf(ea), fb = __expf(eb), fc = __expf(ec), fd = __expf(ee);
        den += (fa + fb) + (fc + fd);
        num += (fa * h0 + fb * h1) + (fc * h3 + fd * h4);
    }
    for (; j < c; ++j) {
        float h0 = h2[bb[j]];
        float ea = h0 * a_s + ad;
        ea = ea > 0.f ? ea : NEG_SLOPE * ea;
        float fa = __expf(ea);
        den += fa;
        num += fa * h0;
    }
    if (dg > SLOT) {
        int on = *ovf_cnt; if (on > OVF_CAP) on = OVF_CAP;
        for (int i = 0; i < on; ++i) {
            unsigned long long e64 = ovf[i];
            if ((int)(e64 & 0xFFFFFFFFu) == n) {
                float h0 = h2[(unsigned)(e64 >> 32)];
                float ea = h0 * a_s + ad;
                ea = ea > 0.f ? ea : NEG_SLOPE * ea;
                float fa = __expf(ea);
                den += fa;
                num += fa * h0;
            }
        }
    }
    out[n] = num / den + b2[0];
}

extern "C" void kernel_launch(void* const* d_in, const int* in_sizes, int n_in,
                              void* d_out, int out_size, void* d_ws, size_t ws_size,
                              hipStream_t stream) {
    const float* x   = (const float*)d_in[0];
    const int*   ei  = (const int*)d_in[1];
    const float* W1  = (const float*)d_in[2];
    const float* as1 = (const float*)d_in[3];
    const float* ad1 = (const float*)d_in[4];
    const float* b1  = (const float*)d_in[5];
    const float* W2  = (const float*)d_in[6];
    const float* as2 = (const float*)d_in[7];
    const float* ad2 = (const float*)d_in[8];
    const float* b2  = (const float*)d_in[9];
    float* out = (float*)d_out;

    int N = in_sizes[0];       // 100000
    int E = in_sizes[1] / 2;   // 1600000

    // Workspace layout (8B-aligned head first):
    // ovf[OVF_CAP] u64 | h2[N] f | deg[N] i | ovf_cnt i | binned[N*SLOT] u32
    unsigned long long* ovf = (unsigned long long*)d_ws;
    float* h2      = (float*)(ovf + OVF_CAP);
    int*   deg     = (int*)(h2 + N);
    int*   ovf_cnt = deg + N;                  // contiguous with deg for one memset
    unsigned int* binned = (unsigned int*)(ovf_cnt + 1);

    int nscat = (E + SCAT_EPB - 1) / SCAT_EPB;   // 391
    int ngath = (N + 255) / 256;                 // 391

    hipMemsetAsync(deg, 0, (size_t)(N + 1) * sizeof(int), stream);
    gat_scatter_kernel<<<nscat, 256, 0, stream>>>(ei, E, deg, ovf_cnt, ovf, binned);
    gat_gather1_kernel<<<ngath, 256, 0, stream>>>(N, x, binned, deg, ovf_cnt, ovf,
                                                  W1, as1, ad1, b1, W2, h2);
    gat_gather2_kernel<<<ngath, 256, 0, stream>>>(N, h2, binned, deg, ovf_cnt, ovf,
                                                  as2, ad2, b2, out);
}

// Round 5
// 133.684 us; speedup vs baseline: 2.2575x; 1.5701x over previous
//
#include <hip/hip_runtime.h>

#define NEG_SLOPE 0.2f
#define EPSV 1e-16f
#define NHEADS 8
#define NCH 16
#define BKT_SHIFT 8        // 256 nodes per bucket
#define BKT_NODES 256
#define CAP 8192           // per-bucket edge capacity (mean 4096, ~64 sigma slack)
#define BIN_TPB 512
#define BIN_EPB 8192       // edges per bin block (16/thread)
#define MAX_BKT 512
#define SLOTL 45           // per-node LDS row slots (Poisson(16) max ~40); odd -> bank-conflict-free
#define ROWW (BKT_NODES * SLOTL)   // 11520 words per bucket row-block
#define GOVF_CAP 8192

// Bin pass (round-1 proven, 512 threads): LDS histogram -> local ranks; one
// global atomic per (block, nonempty bucket); clustered packed writes
// (src<<8 | dst&255). 196 blocks halves per-cursor global atomic depth.
__global__ __launch_bounds__(BIN_TPB) void gat_bin_kernel(
        const int* __restrict__ ei, int E, int nbuckets,
        int* __restrict__ bkt_cnt, unsigned int* __restrict__ binned) {
    __shared__ int hist[MAX_BKT];
    __shared__ int gbase[MAX_BKT];
    int t = threadIdx.x;
    for (int i = t; i < nbuckets; i += BIN_TPB) hist[i] = 0;
    __syncthreads();
    int base = blockIdx.x * BIN_EPB;
    int dv[16];      // retained dst values (compile-time indexed -> registers)
    int lr[16];      // local ranks
#pragma unroll
    for (int k = 0; k < 4; ++k) {
        int idx = base + k * (BIN_TPB * 4) + t * 4;
        if (idx + 3 < E) {
            int4 d4 = *(const int4*)(ei + E + idx);
            dv[4*k+0] = d4.x; dv[4*k+1] = d4.y;
            dv[4*k+2] = d4.z; dv[4*k+3] = d4.w;
        } else {
#pragma unroll
            for (int u = 0; u < 4; ++u)
                dv[4*k+u] = (idx + u < E) ? ei[E + idx + u] : -1;
        }
#pragma unroll
        for (int u = 0; u < 4; ++u)
            lr[4*k+u] = (dv[4*k+u] >= 0)
                ? atomicAdd(&hist[dv[4*k+u] >> BKT_SHIFT], 1) : 0;
    }
    __syncthreads();
    for (int i = t; i < nbuckets; i += BIN_TPB) {
        int c = hist[i];
        gbase[i] = c ? (i * CAP + atomicAdd(&bkt_cnt[i], c)) : 0;
    }
    __syncthreads();
#pragma unroll
    for (int k = 0; k < 4; ++k) {
        int idx = base + k * (BIN_TPB * 4) + t * 4;
        if (idx + 3 < E) {
            int4 s4 = *(const int4*)(ei + idx);
            binned[gbase[dv[4*k+0] >> BKT_SHIFT] + lr[4*k+0]] =
                ((unsigned)s4.x << BKT_SHIFT) | (unsigned)(dv[4*k+0] & (BKT_NODES-1));
            binned[gbase[dv[4*k+1] >> BKT_SHIFT] + lr[4*k+1]] =
                ((unsigned)s4.y << BKT_SHIFT) | (unsigned)(dv[4*k+1] & (BKT_NODES-1));
            binned[gbase[dv[4*k+2] >> BKT_SHIFT] + lr[4*k+2]] =
                ((unsigned)s4.z << BKT_SHIFT) | (unsigned)(dv[4*k+2] & (BKT_NODES-1));
            binned[gbase[dv[4*k+3] >> BKT_SHIFT] + lr[4*k+3]] =
                ((unsigned)s4.w << BKT_SHIFT) | (unsigned)(dv[4*k+3] & (BKT_NODES-1));
        } else {
#pragma unroll
            for (int u = 0; u < 4; ++u)
                if (idx + u < E) {
                    unsigned s = (unsigned)ei[idx + u];
                    int d = dv[4*k+u];
                    binned[gbase[d >> BKT_SHIFT] + lr[4*k+u]] =
                        (s << BKT_SHIFT) | (unsigned)(d & (BKT_NODES-1));
                }
        }
    }
}

// Layer 1: single-pass direct scatter into fixed-stride per-node LDS rows
// (1 LDS atomic per edge, no count pass / scan / cursor pass), per-node
// register gather + fused MLP -> h2; flat coalesced row-block write-back
// for layer 2.
__global__ __launch_bounds__(256) void gat_gather1_kernel(
        int N, const float* __restrict__ x,
        const unsigned int* __restrict__ binned, const int* __restrict__ bkt_cnt,
        const float* __restrict__ W1, const float* __restrict__ as1,
        const float* __restrict__ ad1, const float* __restrict__ b1,
        const float* __restrict__ W2, float* __restrict__ h2out,
        unsigned int* __restrict__ binrows, int* __restrict__ row_deg,
        int* __restrict__ g_ovf_cnt, unsigned long long* __restrict__ g_ovf) {
    __shared__ unsigned int ed[ROWW];          // 45 KB: ed[dl*45 + r]
    __shared__ int cnt[BKT_NODES];
    __shared__ float xloc[BKT_NODES];
    __shared__ float S1s[NHEADS], D1s[NHEADS];
    int b = blockIdx.x, t = threadIdx.x;
    if (t < NHEADS) {
        float s = 0.f, d = 0.f;
        for (int c = 0; c < NCH; ++c) {
            float w = W1[t * NCH + c];
            s += w * as1[t * NCH + c];
            d += w * ad1[t * NCH + c];
        }
        S1s[t] = s; D1s[t] = d;
    }
    int node = (b << BKT_SHIFT) + t;
    xloc[t] = (node < N) ? x[node] : 0.f;
    cnt[t] = 0;
    __syncthreads();
    int nE = bkt_cnt[b]; if (nE > CAP) nE = CAP;
    const unsigned int* bb = binned + (size_t)b * CAP;
    // single pass: load + direct scatter (1 atomic/edge)
    for (int j0 = 0; j0 < nE; j0 += 1024) {
        int idx = j0 + t * 4;
        unsigned v[4]; int nv;
        if (idx + 3 < nE) {
            uint4 q = *(const uint4*)(bb + idx);
            v[0] = q.x; v[1] = q.y; v[2] = q.z; v[3] = q.w; nv = 4;
        } else {
            nv = nE - idx; if (nv < 0) nv = 0; if (nv > 4) nv = 4;
            for (int u = 0; u < nv; ++u) v[u] = bb[idx + u];
        }
        for (int u = 0; u < nv; ++u) {
            unsigned vv = v[u];
            int dl = vv & (BKT_NODES - 1);
            int r = atomicAdd(&cnt[dl], 1);
            if (r < SLOTL) {
                ed[dl * SLOTL + r] = vv >> BKT_SHIFT;
            } else {                               // ~never (needs in-bucket deg>45)
                int o = atomicAdd(g_ovf_cnt, 1);
                if (o < GOVF_CAP)
                    g_ovf[o] = ((unsigned long long)(vv >> BKT_SHIFT) << 32)
                               | (unsigned)((b << BKT_SHIFT) + dl);
            }
        }
    }
    __syncthreads();
    // flat coalesced write-back of the whole row block (clustered: no 64B
    // write amplification, unlike per-node scatter)
    for (int i = t * 4; i < ROWW; i += 1024)
        *(uint4*)(binrows + (size_t)b * ROWW + i) = *(const uint4*)(ed + i);
    int dg = cnt[t];
    if (node < N) row_deg[node] = dg;
    int c = dg < SLOTL ? dg : SLOTL;
    // per-node register gather from own LDS row (stride 45 -> conflict-free)
    float S1[NHEADS], A[NHEADS], den[NHEADS], num[NHEADS];
    float xn = xloc[t];
#pragma unroll
    for (int h = 0; h < NHEADS; ++h) {
        S1[h] = S1s[h];
        A[h] = xn * D1s[h];
        float e = xn * S1[h] + A[h];          // self-loop
        e = e > 0.f ? e : NEG_SLOPE * e;
        float ex = __expf(e);
        den[h] = ex + EPSV;
        num[h] = ex * xn;
    }
    const unsigned int* myrow = ed + t * SLOTL;
    int j = 0;
    for (; j + 4 <= c; j += 4) {
        unsigned e0 = myrow[j], e1 = myrow[j+1], e2 = myrow[j+2], e3 = myrow[j+3];
        float x0 = x[e0], x1 = x[e1], x2 = x[e2], x3 = x[e3];
#pragma unroll
        for (int h = 0; h < NHEADS; ++h) {
            float ea = x0 * S1[h] + A[h]; ea = ea > 0.f ? ea : NEG_SLOPE * ea;
            float eb = x1 * S1[h] + A[h]; eb = eb > 0.f ? eb : NEG_SLOPE * eb;
            float ec = x2 * S1[h] + A[h]; ec = ec > 0.f ? ec : NEG_SLOPE * ec;
            float ee = x3 * S1[h] + A[h]; ee = ee > 0.f ? ee : NEG_SLOPE * ee;
            float fa = __expf(ea), fb = __expf(eb), fc = __expf(ec), fd = __expf(ee);
            den[h] += (fa + fb) + (fc + fd);
            num[h] += (fa * x0 + fb * x1) + (fc * x2 + fd * x3);
        }
    }
    for (; j < c; ++j) {
        float x0 = x[myrow[j]];
#pragma unroll
        for (int h = 0; h < NHEADS; ++h) {
            float ea = x0 * S1[h] + A[h];
            ea = ea > 0.f ? ea : NEG_SLOPE * ea;
            float fa = __expf(ea);
            den[h] += fa;
            num[h] += fa * x0;
        }
    }
    if (dg > SLOTL) {                          // guarded overflow scan (normally dead)
        int on = *g_ovf_cnt; if (on > GOVF_CAP) on = GOVF_CAP;
        for (int i = 0; i < on; ++i) {
            unsigned long long e64 = g_ovf[i];
            if ((int)(unsigned)(e64 & 0xFFFFFFFFu) == node) {
                float x0 = x[(unsigned)(e64 >> 32)];
#pragma unroll
                for (int h = 0; h < NHEADS; ++h) {
                    float ea = x0 * S1[h] + A[h];
                    ea = ea > 0.f ? ea : NEG_SLOPE * ea;
                    float fa = __expf(ea);
                    den[h] += fa;
                    num[h] += fa * x0;
                }
            }
        }
    }
    if (node >= N) return;
    float acc = 0.f;
#pragma unroll
    for (int h = 0; h < NHEADS; ++h) {
        float z = num[h] / den[h];
#pragma unroll
        for (int cc = 0; cc < NCH; ++cc) {
            int k = h * NCH + cc;
            float vv = W1[k] * z + b1[k];
            vv = vv > 0.f ? vv : (__expf(vv) - 1.f);   // elu
            acc += vv * W2[k];
        }
    }
    h2out[node] = acc;
}

// Layer 2: node-parallel gather over the persisted fixed-stride rows
// (row for node n starts at binrows + n*SLOTL).
__global__ __launch_bounds__(256) void gat_gather2_kernel(
        int N, const float* __restrict__ h2,
        const unsigned int* __restrict__ binrows, const int* __restrict__ row_deg,
        const int* __restrict__ g_ovf_cnt, const unsigned long long* __restrict__ g_ovf,
        const float* __restrict__ as2p, const float* __restrict__ ad2p,
        const float* __restrict__ b2, float* __restrict__ out) {
    int n = blockIdx.x * 256 + threadIdx.x;
    if (n >= N) return;
    float a_s = as2p[0], a_d = ad2p[0];
    float hn = h2[n];
    float ad = hn * a_d;
    float e = hn * a_s + ad;                         // self-loop
    e = e > 0.f ? e : NEG_SLOPE * e;
    float ex = __expf(e);
    float den = ex + EPSV;
    float num = ex * hn;
    int dg = row_deg[n];
    int c = dg < SLOTL ? dg : SLOTL;
    const unsigned int* myrow = binrows + (size_t)n * SLOTL;
    int j = 0;
    for (; j + 4 <= c; j += 4) {
        unsigned e0 = myrow[j], e1 = myrow[j+1], e2 = myrow[j+2], e3 = myrow[j+3];
        float h0 = h2[e0], h1 = h2[e1], h3 = h2[e2], h4 = h2[e3];
        float ea = h0 * a_s + ad; ea = ea > 0.f ? ea : NEG_SLOPE * ea;
        float eb = h1 * a_s + ad; eb = eb > 0.f ? eb : NEG_SLOPE * eb;
        float ec = h3 * a_s + ad; ec = ec > 0.f ? ec : NEG_SLOPE * ec;
        float ee = h4 * a_s + ad; ee = ee > 0.f ? ee : NEG_SLOPE * ee;
        float fa = __expf(ea), fb = __expf(eb), fc = __expf(ec), fd = __expf(ee);
        den += (fa + fb) + (fc + fd);
        num += (fa * h0 + fb * h1) + (fc * h3 + fd * h4);
    }
    for (; j < c; ++j) {
        float h0 = h2[myrow[j]];
        float ea = h0 * a_s + ad;
        ea = ea > 0.f ? ea : NEG_SLOPE * ea;
        float fa = __expf(ea);
        den += fa;
        num += fa * h0;
    }
    if (dg > SLOTL) {
        int on = *g_ovf_cnt; if (on > GOVF_CAP) on = GOVF_CAP;
        for (int i = 0; i < on; ++i) {
            unsigned long long e64 = g_ovf[i];
            if ((int)(unsigned)(e64 & 0xFFFFFFFFu) == n) {
                float h0 = h2[(unsigned)(e64 >> 32)];
                float ea = h0 * a_s + ad;
                ea = ea > 0.f ? ea : NEG_SLOPE * ea;
                float fa = __expf(ea);
                den += fa;
                num += fa * h0;
            }
        }
    }
    out[n] = num / den + b2[0];
}

extern "C" void kernel_launch(void* const* d_in, const int* in_sizes, int n_in,
                              void* d_out, int out_size, void* d_ws, size_t ws_size,
                              hipStream_t stream) {
    const float* x   = (const float*)d_in[0];
    const int*   ei  = (const int*)d_in[1];
    const float* W1  = (const float*)d_in[2];
    const float* as1 = (const float*)d_in[3];
    const float* ad1 = (const float*)d_in[4];
    const float* b1  = (const float*)d_in[5];
    const float* W2  = (const float*)d_in[6];
    const float* as2 = (const float*)d_in[7];
    const float* ad2 = (const float*)d_in[8];
    const float* b2  = (const float*)d_in[9];
    float* out = (float*)d_out;

    int N = in_sizes[0];       // 100000
    int E = in_sizes[1] / 2;   // 1600000

    int nbuckets = (N + BKT_NODES - 1) >> BKT_SHIFT;   // 391
    int nbin     = (E + BIN_EPB - 1) / BIN_EPB;        // 196
    int ngath    = nbuckets;                           // 391

    // Workspace (d_ws 256B-aligned; all segment sizes keep 16B alignment):
    // h2[N]f | row_deg[N]i | bkt_cnt[nb]i | g_ovf_cnt[1]i | g_ovf[8192]u64 |
    // binned[nb*CAP]u32 | binrows[nb*ROWW]u32      (~32 MB of 268 MB)
    float* h2        = (float*)d_ws;
    int*   row_deg   = (int*)(h2 + N);
    int*   bkt_cnt   = row_deg + N;
    int*   g_ovf_cnt = bkt_cnt + nbuckets;
    unsigned long long* g_ovf = (unsigned long long*)(g_ovf_cnt + 1);
    unsigned int* binned  = (unsigned int*)(g_ovf + GOVF_CAP);
    unsigned int* binrows = binned + (size_t)nbuckets * CAP;

    // zero bkt_cnt + g_ovf_cnt in one tiny memset (replaces setup kernel)
    hipMemsetAsync(bkt_cnt, 0, (size_t)(nbuckets + 1) * sizeof(int), stream);
    gat_bin_kernel<<<nbin, BIN_TPB, 0, stream>>>(ei, E, nbuckets, bkt_cnt, binned);
    gat_gather1_kernel<<<ngath, 256, 0, stream>>>(N, x, binned, bkt_cnt,
                                                  W1, as1, ad1, b1, W2, h2,
                                                  binrows, row_deg,
                                                  g_ovf_cnt, g_ovf);
    gat_gather2_kernel<<<(N + 255) / 256, 256, 0, stream>>>(
        N, h2, binrows, row_deg, g_ovf_cnt, g_ovf, as2, ad2, b2, out);
}